// Round 10
// baseline (348.965 us; speedup 1.0000x reference)
//
#include <hip/hip_runtime.h>

#define B_ 4
#define T_ 2048
#define C_ 1024
#define H_ 16
#define D_ 64
#define EPS_ 1.1920929e-07f
#define QSCALE 0.18033688f  // 0.125 * log2(e): folds attn scale AND exp2 conversion

typedef __attribute__((ext_vector_type(8))) short bf16x8;
typedef __attribute__((ext_vector_type(4))) float f32x4;
typedef unsigned short u16;
typedef unsigned int u32;

__device__ inline u16 f2bf(float f) {
  unsigned u = __float_as_uint(f);
  unsigned r = (u + 0x7fffu + ((u >> 16) & 1u)) >> 16;
  return (u16)r;
}

// ---------------- f32 -> bf16 conversion (x) ----------------
__global__ __launch_bounds__(256) void cvt_bf16(const float* __restrict__ src,
                                                u16* __restrict__ dst, int n) {
  const int i = (blockIdx.x * 256 + threadIdx.x) * 4;
  if (i < n) {
    float4 v = *(const float4*)&src[i];
    ushort4 o;
    o.x = f2bf(v.x); o.y = f2bf(v.y); o.z = f2bf(v.z); o.w = f2bf(v.w);
    *(ushort4*)&dst[i] = o;
  }
}

// ---------------- all 4 weights in one launch ----------------
__global__ __launch_bounds__(256) void cvt_weights(const float* __restrict__ wq,
                                                   const float* __restrict__ wk,
                                                   const float* __restrict__ wv,
                                                   const float* __restrict__ wo,
                                                   u16* __restrict__ wqkv,
                                                   u16* __restrict__ wob, int n) {
  const int i = (blockIdx.x * 256 + threadIdx.x) * 4;
  const int t = blockIdx.y;
  const float* src = (t == 0) ? wq : (t == 1) ? wk : (t == 2) ? wv : wo;
  u16* dst = (t == 3) ? wob : (wqkv + (size_t)t * n);
  if (i < n) {
    float4 v = *(const float4*)&src[i];
    ushort4 o;
    o.x = f2bf(v.x); o.y = f2bf(v.y); o.z = f2bf(v.z); o.w = f2bf(v.w);
    *(ushort4*)&dst[i] = o;
  }
}

// ---------------- fused QKV GEMM: [Q|K|V] = X @ Wqkv^T + epilogues ----------------
// blockIdx.x: 0..7 -> Q (rope+rms, *QSCALE), 8..15 -> K (rope+rms), 16..23 -> V.
__global__ __launch_bounds__(256) void gemm_qkv(const u16* __restrict__ X,
                                                const u16* __restrict__ W,
                                                u16* __restrict__ qb,
                                                u16* __restrict__ kb,
                                                u16* __restrict__ vb,
                                                const float* __restrict__ cs,
                                                const float* __restrict__ sn,
                                                int M, int K) {
  __shared__ short As[128 * 64];
  __shared__ short Bs[128 * 64];
  const int tid = threadIdx.x;
  const int lane = tid & 63;
  const int w = tid >> 6;
  const int wr = w >> 1, wc = w & 1;
  const int m0 = blockIdx.y * 128, n0 = blockIdx.x * 128;
  const int srow = lane >> 3;
  const int scol = (lane & 7) * 8;

  f32x4 acc[4][4];
#pragma unroll
  for (int mi = 0; mi < 4; ++mi)
#pragma unroll
    for (int ni = 0; ni < 4; ++ni)
      acc[mi][ni] = (f32x4){0.f, 0.f, 0.f, 0.f};

  const int r = lane & 15;
  const int quad = lane >> 4;

  bf16x8 av[4], bv[4];
#pragma unroll
  for (int i = 0; i < 4; ++i) {
    const int row = w * 32 + i * 8 + srow;
    av[i] = *(const bf16x8*)&X[(size_t)(m0 + row) * K + scol];
    bv[i] = *(const bf16x8*)&W[(size_t)(n0 + row) * K + scol];
  }

  for (int kt = 0; kt < K; kt += 64) {
#pragma unroll
    for (int i = 0; i < 4; ++i) {
      const int row = w * 32 + i * 8 + srow;
      *(bf16x8*)&As[row * 64 + scol] = av[i];
      *(bf16x8*)&Bs[row * 64 + scol] = bv[i];
    }
    __syncthreads();
    if (kt + 64 < K) {
#pragma unroll
      for (int i = 0; i < 4; ++i) {
        const int row = w * 32 + i * 8 + srow;
        av[i] = *(const bf16x8*)&X[(size_t)(m0 + row) * K + kt + 64 + scol];
        bv[i] = *(const bf16x8*)&W[(size_t)(n0 + row) * K + kt + 64 + scol];
      }
    }
#pragma unroll
    for (int kc = 0; kc < 2; ++kc) {
      const int ko = kc * 32 + quad * 8;
      bf16x8 a[4], b[4];
#pragma unroll
      for (int mi = 0; mi < 4; ++mi)
        a[mi] = *(const bf16x8*)&As[(wr * 64 + mi * 16 + r) * 64 + ko];
#pragma unroll
      for (int ni = 0; ni < 4; ++ni)
        b[ni] = *(const bf16x8*)&Bs[(wc * 64 + ni * 16 + r) * 64 + ko];
#pragma unroll
      for (int mi = 0; mi < 4; ++mi)
#pragma unroll
        for (int ni = 0; ni < 4; ++ni)
          acc[mi][ni] = __builtin_amdgcn_mfma_f32_16x16x32_bf16(a[mi], b[ni], acc[mi][ni], 0, 0, 0);
    }
    __syncthreads();
  }

  const int which = blockIdx.x >> 3;                // 0=Q 1=K 2=V
  const int c0 = (blockIdx.x & 7) * 128 + wc * 64;  // one head per wave
  u16* dst = (which == 0) ? qb : (which == 1) ? kb : vb;

  if (which < 2) {
#pragma unroll
    for (int mi = 0; mi < 4; ++mi)
#pragma unroll
      for (int j = 0; j < 4; ++j) {
        const int gr = m0 + wr * 64 + mi * 16 + quad * 4 + j;
        const int t = gr & (T_ - 1);
        float o[4];
#pragma unroll
        for (int ni = 0; ni < 2; ++ni) {
          const float c = cs[t * 32 + ni * 16 + r];
          const float s = sn[t * 32 + ni * 16 + r];
          const float x1 = acc[mi][ni][j], x2 = acc[mi][ni + 2][j];
          o[ni]     = x1 * c + x2 * s;
          o[ni + 2] = x2 * c - x1 * s;
        }
        float sq = o[0] * o[0] + o[1] * o[1] + o[2] * o[2] + o[3] * o[3];
        sq += __shfl_xor(sq, 1, 64);
        sq += __shfl_xor(sq, 2, 64);
        sq += __shfl_xor(sq, 4, 64);
        sq += __shfl_xor(sq, 8, 64);
        float rn = rsqrtf(sq * (1.0f / 64.0f) + EPS_);
        if (which == 0) rn *= QSCALE;  // attn scale + log2e for exp2 softmax
#pragma unroll
        for (int ni = 0; ni < 4; ++ni)
          dst[(size_t)gr * C_ + c0 + ni * 16 + r] = f2bf(o[ni] * rn);
      }
  } else {
#pragma unroll
    for (int mi = 0; mi < 4; ++mi)
#pragma unroll
      for (int ni = 0; ni < 4; ++ni) {
        const int gc = c0 + ni * 16 + r;
#pragma unroll
        for (int j = 0; j < 4; ++j) {
          const int gr = m0 + wr * 64 + mi * 16 + quad * 4 + j;
          dst[(size_t)gr * C_ + gc] = f2bf(acc[mi][ni][j]);
        }
      }
  }
}

// ---------------- output GEMM: out = Y @ Wo^T (fp32 out) ----------------
__global__ __launch_bounds__(256) void gemm_out(const u16* __restrict__ X,
                                                const u16* __restrict__ W,
                                                float* __restrict__ Y,
                                                int M, int N, int K) {
  __shared__ short As[128 * 64];
  __shared__ short Bs[128 * 64];
  const int tid = threadIdx.x;
  const int lane = tid & 63;
  const int w = tid >> 6;
  const int wr = w >> 1, wc = w & 1;
  const int m0 = blockIdx.y * 128, n0 = blockIdx.x * 128;
  const int srow = lane >> 3;
  const int scol = (lane & 7) * 8;

  f32x4 acc[4][4];
#pragma unroll
  for (int mi = 0; mi < 4; ++mi)
#pragma unroll
    for (int ni = 0; ni < 4; ++ni)
      acc[mi][ni] = (f32x4){0.f, 0.f, 0.f, 0.f};

  const int r = lane & 15;
  const int quad = lane >> 4;

  bf16x8 av[4], bv[4];
#pragma unroll
  for (int i = 0; i < 4; ++i) {
    const int row = w * 32 + i * 8 + srow;
    av[i] = *(const bf16x8*)&X[(size_t)(m0 + row) * K + scol];
    bv[i] = *(const bf16x8*)&W[(size_t)(n0 + row) * K + scol];
  }

  for (int kt = 0; kt < K; kt += 64) {
#pragma unroll
    for (int i = 0; i < 4; ++i) {
      const int row = w * 32 + i * 8 + srow;
      *(bf16x8*)&As[row * 64 + scol] = av[i];
      *(bf16x8*)&Bs[row * 64 + scol] = bv[i];
    }
    __syncthreads();
    if (kt + 64 < K) {
#pragma unroll
      for (int i = 0; i < 4; ++i) {
        const int row = w * 32 + i * 8 + srow;
        av[i] = *(const bf16x8*)&X[(size_t)(m0 + row) * K + kt + 64 + scol];
        bv[i] = *(const bf16x8*)&W[(size_t)(n0 + row) * K + kt + 64 + scol];
      }
    }
#pragma unroll
    for (int kc = 0; kc < 2; ++kc) {
      const int ko = kc * 32 + quad * 8;
      bf16x8 a[4], b[4];
#pragma unroll
      for (int mi = 0; mi < 4; ++mi)
        a[mi] = *(const bf16x8*)&As[(wr * 64 + mi * 16 + r) * 64 + ko];
#pragma unroll
      for (int ni = 0; ni < 4; ++ni)
        b[ni] = *(const bf16x8*)&Bs[(wc * 64 + ni * 16 + r) * 64 + ko];
#pragma unroll
      for (int mi = 0; mi < 4; ++mi)
#pragma unroll
        for (int ni = 0; ni < 4; ++ni)
          acc[mi][ni] = __builtin_amdgcn_mfma_f32_16x16x32_bf16(a[mi], b[ni], acc[mi][ni], 0, 0, 0);
    }
    __syncthreads();
  }

#pragma unroll
  for (int mi = 0; mi < 4; ++mi)
#pragma unroll
    for (int ni = 0; ni < 4; ++ni) {
      const int gc = n0 + wc * 64 + ni * 16 + r;
#pragma unroll
      for (int j = 0; j < 4; ++j) {
        const int gr = m0 + wr * 64 + mi * 16 + quad * 4 + j;
        Y[(size_t)gr * N + gc] = acc[mi][ni][j];
      }
    }
}

// ---------------- MFMA flash attention ----------------
// Fixed-shift softmax via exp2 (log2e folded into Q). Q frags direct from
// global (A-frag = 8 contiguous d-values). Ps wave-local (16 rows/wave,
// reused across q-groups; within-wave DS ordering makes it barrier-free).
// grid=(T/128, B*H), block=256; wave w owns queries [w*32, w*32+32).
__global__ __launch_bounds__(256) void flash_mfma(const u16* __restrict__ Qb,
                                                  const u16* __restrict__ Kb,
                                                  const u16* __restrict__ Vb,
                                                  u16* __restrict__ Yb) {
  __shared__ u16 Ks[64][72];
  __shared__ u16 Vt[64][72];  // Vt[d][slot], slot=(key&15)*4+(key>>4)
  __shared__ u16 Ps[64][72];  // P tiles, wave-local rows [w*16, w*16+16)
  const int tid = threadIdx.x;
  const int lane = tid & 63;
  const int w = tid >> 6;
  const int r = lane & 15;
  const int quad = lane >> 4;
  const int qt = blockIdx.x, bh = blockIdx.y;
  const int b = bh >> 4, h = bh & 15;
  const int srow = lane;
  const int sd0 = w * 16;
  const int vslot = (srow & 15) * 4 + (srow >> 4);

  // Q fragments straight from global: row qt*128+w*32+qg*16+r, cols kc*32+quad*8
  bf16x8 qf[2][2];
#pragma unroll
  for (int qg = 0; qg < 2; ++qg) {
    const size_t g = ((size_t)((b * T_ + qt * 128 + w * 32 + qg * 16 + r) * H_ + h)) * D_;
#pragma unroll
    for (int kc = 0; kc < 2; ++kc)
      qf[qg][kc] = *(const bf16x8*)&Qb[g + kc * 32 + quad * 8];
  }

  f32x4 oacc[2][4];
#pragma unroll
  for (int qg = 0; qg < 2; ++qg)
#pragma unroll
    for (int ni = 0; ni < 4; ++ni) oacc[qg][ni] = (f32x4){0.f, 0.f, 0.f, 0.f};
  float l_i[2][4];
#pragma unroll
  for (int qg = 0; qg < 2; ++qg)
#pragma unroll
    for (int j = 0; j < 4; ++j) l_i[qg][j] = 0.f;

  bf16x8 k0, k1, v0, v1;
  {
    const size_t g = ((size_t)((b * T_ + srow) * H_ + h)) * D_ + sd0;
    k0 = *(const bf16x8*)&Kb[g];
    k1 = *(const bf16x8*)&Kb[g + 8];
    v0 = *(const bf16x8*)&Vb[g];
    v1 = *(const bf16x8*)&Vb[g + 8];
  }

  for (int kt = 0; kt < T_; kt += 64) {
    *(bf16x8*)&Ks[srow][sd0] = k0;
    *(bf16x8*)&Ks[srow][sd0 + 8] = k1;
#pragma unroll
    for (int i = 0; i < 8; ++i) Vt[sd0 + i][vslot] = (u16)v0[i];
#pragma unroll
    for (int i = 0; i < 8; ++i) Vt[sd0 + 8 + i][vslot] = (u16)v1[i];
    __syncthreads();
    if (kt + 64 < T_) {
      const size_t g = ((size_t)((b * T_ + kt + 64 + srow) * H_ + h)) * D_ + sd0;
      k0 = *(const bf16x8*)&Kb[g];
      k1 = *(const bf16x8*)&Kb[g + 8];
      v0 = *(const bf16x8*)&Vb[g];
      v1 = *(const bf16x8*)&Vb[g + 8];
    }

#pragma unroll
    for (int qg = 0; qg < 2; ++qg) {
      f32x4 s[4];
#pragma unroll
      for (int ni = 0; ni < 4; ++ni) {
        s[ni] = (f32x4){0.f, 0.f, 0.f, 0.f};
#pragma unroll
        for (int kc = 0; kc < 2; ++kc) {
          bf16x8 kf = *(const bf16x8*)&Ks[ni * 16 + r][kc * 32 + quad * 8];
          s[ni] = __builtin_amdgcn_mfma_f32_16x16x32_bf16(qf[qg][kc], kf, s[ni], 0, 0, 0);
        }
      }
      // p = exp2(s) (= e^{orig s}); truncating bf16 pack (2 vals / 3 ops)
#pragma unroll
      for (int j = 0; j < 4; ++j) {
        const float p0 = exp2f(s[0][j]);
        const float p1 = exp2f(s[1][j]);
        const float p2 = exp2f(s[2][j]);
        const float p3 = exp2f(s[3][j]);
        l_i[qg][j] += (p0 + p1) + (p2 + p3);
        const u32 lo = (__float_as_uint(p0) >> 16) | (__float_as_uint(p1) & 0xffff0000u);
        const u32 hi = (__float_as_uint(p2) >> 16) | (__float_as_uint(p3) & 0xffff0000u);
        const int prow = w * 16 + quad * 4 + j;
        *(uint2*)&Ps[prow][r * 4] = make_uint2(lo, hi);  // slots r*4+ni
      }
      // O += P @ V (slot space)
#pragma unroll
      for (int kc = 0; kc < 2; ++kc) {
        bf16x8 pf = *(const bf16x8*)&Ps[w * 16 + r][kc * 32 + quad * 8];
#pragma unroll
        for (int ni = 0; ni < 4; ++ni) {
          bf16x8 vf = *(const bf16x8*)&Vt[ni * 16 + r][kc * 32 + quad * 8];
          oacc[qg][ni] = __builtin_amdgcn_mfma_f32_16x16x32_bf16(pf, vf, oacc[qg][ni], 0, 0, 0);
        }
      }
    }
    __syncthreads();
  }

#pragma unroll
  for (int qg = 0; qg < 2; ++qg)
#pragma unroll
    for (int j = 0; j < 4; ++j) {
      float l = l_i[qg][j];
      l += __shfl_xor(l, 1, 64);
      l += __shfl_xor(l, 2, 64);
      l += __shfl_xor(l, 4, 64);
      l += __shfl_xor(l, 8, 64);
      const float inv = 1.0f / l;
      const int t = qt * 128 + w * 32 + qg * 16 + quad * 4 + j;
      const size_t gbase = ((size_t)((b * T_ + t) * H_ + h)) * D_;
#pragma unroll
      for (int ni = 0; ni < 4; ++ni)
        Yb[gbase + ni * 16 + r] = f2bf(oacc[qg][ni][j] * inv);
    }
}

extern "C" void kernel_launch(void* const* d_in, const int* in_sizes, int n_in,
                              void* d_out, int out_size, void* d_ws, size_t ws_size,
                              hipStream_t stream) {
  const float* x    = (const float*)d_in[0];
  const float* cosb = (const float*)d_in[1];
  const float* sinb = (const float*)d_in[2];
  const float* Wq   = (const float*)d_in[3];
  const float* Wk   = (const float*)d_in[4];
  const float* Wv   = (const float*)d_in[5];
  const float* Wo   = (const float*)d_in[6];
  float* out = (float*)d_out;

  const size_t NE = (size_t)B_ * T_ * C_;  // 8M elements
  const int CC = C_ * C_;                  // 1M elements
  u16* xb   = (u16*)d_ws;
  u16* qb   = xb + NE;
  u16* kb   = qb + NE;
  u16* vb   = kb + NE;
  u16* wqkv = vb + NE;
  u16* wob  = wqkv + 3 * (size_t)CC;
  u16* yb   = xb;  // xb dead after QKV GEMM; reuse for attention output

  const int M = B_ * T_;  // 8192

  cvt_bf16<<<(int)(NE / 1024), 256, 0, stream>>>(x, xb, (int)NE);
  dim3 wg(CC / 1024, 4);
  cvt_weights<<<wg, 256, 0, stream>>>(Wq, Wk, Wv, Wo, wqkv, wob, CC);

  dim3 qg(24, M / 128), gb(256);
  gemm_qkv<<<qg, gb, 0, stream>>>(xb, wqkv, qb, kb, vb, cosb, sinb, M, C_);

  dim3 fg(T_ / 128, B_ * H_);
  flash_mfma<<<fg, 256, 0, stream>>>(qb, kb, vb, yb);

  dim3 og(C_ / 128, M / 128);
  gemm_out<<<og, gb, 0, stream>>>(yb, wob, out, M, C_, C_);
}